// Round 2
// baseline (184.546 us; speedup 1.0000x reference)
//
#include <hip/hip_runtime.h>
#include <math.h>

constexpr int HD   = 512;    // hidden
constexpr int LL   = 1024;   // SES*SEQ
constexpr int MT   = 16384;  // B*L rows
constexpr int KNBR = 32;     // K neighbors
constexpr float SCL = 0.04419417382415922f;  // 1/sqrt(512)

typedef __attribute__((ext_vector_type(8))) short  bf16x8;  // 8 bf16 = 4 VGPRs
typedef __attribute__((ext_vector_type(4))) float  f32x4;

__device__ inline float b2f(unsigned short u) {
    union { unsigned int i; float f; } v; v.i = (unsigned int)u << 16; return v.f;
}
__device__ inline float b2f_lo(unsigned int u) {
    union { unsigned int i; float f; } v; v.i = u << 16; return v.f;
}
__device__ inline float b2f_hi(unsigned int u) {
    union { unsigned int i; float f; } v; v.i = u & 0xffff0000u; return v.f;
}
__device__ inline unsigned short f2b(float x) {
    union { float f; unsigned int u; } v; v.f = x;
    unsigned int r = v.u + 0x7fff + ((v.u >> 16) & 1);
    return (unsigned short)(r >> 16);
}

// ================= prep: convs + q-projection, one launch ==================
constexpr int PB_CONV_I = 8192;
constexpr int PB_CONV_W = 512;
constexpr int PB_Q      = 2048;

__global__ __launch_bounds__(256) void prep(
    const float* __restrict__ item, const float* __restrict__ Wv,
    const float* __restrict__ Wd, const float* __restrict__ u,
    const float* __restrict__ Wq, const float* __restrict__ bq,
    unsigned short* __restrict__ item_bf, unsigned short* __restrict__ Wv_bf,
    unsigned short* __restrict__ Wd_bf, float* __restrict__ q)
{
    const int blk = blockIdx.x, tid = threadIdx.x;

    if (blk < PB_CONV_I) {
        const int i = blk * 1024 + tid * 4;
        float4 v = *(const float4*)&item[i];
        ushort4 o;
        o.x = f2b(v.x); o.y = f2b(v.y); o.z = f2b(v.z); o.w = f2b(v.w);
        *(ushort4*)&item_bf[i] = o;
        return;
    }
    if (blk < PB_CONV_I + PB_CONV_W) {
        const int n = HD*HD;
        const int i = (blk - PB_CONV_I) * 1024 + tid * 4;
        const float* s; unsigned short* d; int off;
        if (i < n) { s = Wv; d = Wv_bf; off = i; }
        else       { s = Wd; d = Wd_bf; off = i - n; }
        float4 v = *(const float4*)&s[off];
        ushort4 o;
        o.x = f2b(v.x); o.y = f2b(v.y); o.z = f2b(v.z); o.w = f2b(v.w);
        *(ushort4*)&d[off] = o;
        return;
    }
    {   // q[b][h], one wave per (b,h)
        const int wid  = (blk - PB_CONV_I - PB_CONV_W) * 4 + (tid >> 6);
        const int lane = tid & 63;
        const int b = wid >> 9, h = wid & 511;
        const float* ur = &u[b*HD + lane*8];
        const float* wr = &Wq[(size_t)h*HD + lane*8];
        const float4 u0 = *(const float4*)ur, u1 = *(const float4*)(ur+4);
        const float4 w0 = *(const float4*)wr, w1 = *(const float4*)(wr+4);
        float acc = u0.x*w0.x + u0.y*w0.y + u0.z*w0.z + u0.w*w0.w
                  + u1.x*w1.x + u1.y*w1.y + u1.z*w1.z + u1.w*w1.w;
        #pragma unroll
        for (int off = 32; off; off >>= 1) acc += __shfl_down(acc, off);
        if (lane == 0) q[b*HD + h] = acc + bq[h];
    }
}

// ======= gemm_v_r: V GEMM + r matvec + s0, one launch =======
__global__ __launch_bounds__(256) void gemm_v_r(
    const unsigned short* __restrict__ A, const unsigned short* __restrict__ W,
    const float* __restrict__ bv, const float* __restrict__ Wk,
    const float* __restrict__ bk, const float* __restrict__ q,
    unsigned short* __restrict__ v_bf, float* __restrict__ rbuf,
    float* __restrict__ s0buf)
{
    __shared__ unsigned short As[2][128 * 32];   // 2 x 8 KB
    __shared__ unsigned short Bs[2][128 * 32];   // 2 x 8 KB

    const int blk = blockIdx.x;
    const int tid = threadIdx.x;

    if (blk >= 512) {
        if (blk < 640) {
            __shared__ float red[4][64];
            const int rblk = blk - 512;
            const int b = rblk >> 3, c0 = (rblk & 7) * 64;
            const int cl = tid & 63, hg = tid >> 6;
            const float* qb = &q[b*HD];
            const float* wb = &Wk[(size_t)hg*128*HD + c0 + cl];
            float acc = 0.f;
            #pragma unroll 8
            for (int h = 0; h < 128; h++)
                acc += qb[hg*128 + h] * wb[(size_t)h*HD];
            red[hg][cl] = acc;
            __syncthreads();
            if (tid < 64)
                rbuf[b*HD + c0 + tid] = SCL *
                    (red[0][tid] + red[1][tid] + red[2][tid] + red[3][tid]);
        } else {
            __shared__ float sp[4];
            const int b = blk - 640;
            float p = q[b*HD + tid]*bk[tid] + q[b*HD + tid + 256]*bk[tid + 256];
            #pragma unroll
            for (int off = 32; off; off >>= 1) p += __shfl_down(p, off);
            if ((tid & 63) == 0) sp[tid >> 6] = p;
            __syncthreads();
            if (tid == 0) s0buf[b] = (sp[0] + sp[1] + sp[2] + sp[3]) * SCL;
        }
        return;
    }

    // ---- V GEMM tile ----
    const int rowb = (blk & 7) | ((blk >> 5) << 3);   // 0..127
    const int colb = (blk >> 3) & 3;                  // 0..3
    const int row0 = rowb * 128;
    const int col0 = colb * 128;

    const int wave = tid >> 6, lane = tid & 63;
    const int wm = (wave >> 1) * 64;
    const int wn = (wave & 1)  * 64;

    const int lrr = lane >> 2;
    const int cc  = lane & 3;
    int st_row[2], st_gchunk[2];
    #pragma unroll
    for (int t = 0; t < 2; t++) {
        const int m = wave*32 + t*16 + lrr;
        st_row[t]    = m;
        st_gchunk[t] = cc ^ ((m >> 1) & 3);
    }

    const int fr   = lane & 15;
    const int quad = lane >> 4;

    f32x4 acc[4][4];
    #pragma unroll
    for (int i = 0; i < 4; i++)
        #pragma unroll
        for (int j = 0; j < 4; j++)
            acc[i][j] = (f32x4){0.f, 0.f, 0.f, 0.f};

    int a_off[4], b_off[4];
    #pragma unroll
    for (int i = 0; i < 4; i++) {
        const int m = wm + i*16 + fr;
        a_off[i] = m*32 + ((quad ^ ((m >> 1) & 3)) << 3);
        const int n = wn + i*16 + fr;
        b_off[i] = n*32 + ((quad ^ ((n >> 1) & 3)) << 3);
    }

    auto stage = [&](int bf, int k0) {
        #pragma unroll
        for (int t = 0; t < 2; t++) {
            const int m = st_row[t];
            const unsigned short* ga = &A[(size_t)(row0 + m)*HD + k0 + st_gchunk[t]*8];
            __builtin_amdgcn_global_load_lds(
                (const __attribute__((address_space(1))) void*)ga,
                (__attribute__((address_space(3))) void*)&As[bf][(wave*32 + t*16)*32],
                16, 0, 0);
            const unsigned short* gw = &W[(size_t)(col0 + m)*HD + k0 + st_gchunk[t]*8];
            __builtin_amdgcn_global_load_lds(
                (const __attribute__((address_space(1))) void*)gw,
                (__attribute__((address_space(3))) void*)&Bs[bf][(wave*32 + t*16)*32],
                16, 0, 0);
        }
    };

    stage(0, 0);
    __syncthreads();
    int cur = 0;
    for (int k0 = 0; k0 < HD; k0 += 32) {
        if (k0 + 32 < HD) stage(cur ^ 1, k0 + 32);

        bf16x8 af[4], bfr[4];
        #pragma unroll
        for (int i = 0; i < 4; i++) {
            af[i]  = *(const bf16x8*)&As[cur][a_off[i]];
            bfr[i] = *(const bf16x8*)&Bs[cur][b_off[i]];
        }
        #pragma unroll
        for (int i = 0; i < 4; i++)
            #pragma unroll
            for (int j = 0; j < 4; j++)
                acc[i][j] = __builtin_amdgcn_mfma_f32_16x16x32_bf16(
                    af[i], bfr[j], acc[i][j], 0, 0, 0);
        __syncthreads();
        cur ^= 1;
    }

    #pragma unroll
    for (int j = 0; j < 4; j++) {
        const int col = col0 + wn + j*16 + fr;
        const float bb = bv[col];
        #pragma unroll
        for (int i = 0; i < 4; i++) {
            #pragma unroll
            for (int r = 0; r < 4; r++) {
                const int row = row0 + wm + i*16 + quad*4 + r;
                v_bf[(size_t)row*HD + col] = f2b(acc[i][j][r] + bb);
            }
        }
    }
}

// ------- scores[m] = r[b] . item_bf[m] + s0[b], one wave per row -------
__global__ __launch_bounds__(256) void gp_scores(
    const float* __restrict__ rbuf, const float* __restrict__ s0buf,
    const unsigned short* __restrict__ item_bf, float* __restrict__ scores)
{
    const int m = blockIdx.x * 4 + (threadIdx.x >> 6);
    const int lane = threadIdx.x & 63;
    const int b = m >> 10;
    const unsigned short* ir = &item_bf[(size_t)m*HD + lane*8];
    const uint4 iv = *(const uint4*)ir;
    const float* rr = &rbuf[b*HD + lane*8];
    const float4 r0 = *(const float4*)rr;
    const float4 r1 = *(const float4*)(rr + 4);
    float acc = r0.x*b2f_lo(iv.x) + r0.y*b2f_hi(iv.x)
              + r0.z*b2f_lo(iv.y) + r0.w*b2f_hi(iv.y)
              + r1.x*b2f_lo(iv.z) + r1.y*b2f_hi(iv.z)
              + r1.z*b2f_lo(iv.w) + r1.w*b2f_hi(iv.w);
    #pragma unroll
    for (int off = 32; off; off >>= 1) acc += __shfl_down(acc, off);
    if (lane == 0) scores[m] = acc + s0buf[b];
}

// ----- gather + softmax + weighted sum of v: one wave per row -----
__global__ __launch_bounds__(256) void gp_attn(
    const float* __restrict__ scores, const int* __restrict__ index,
    const float* __restrict__ mask, const unsigned short* __restrict__ v,
    unsigned short* __restrict__ attn)
{
    const int bid = blockIdx.x;
    const int m = ((bid & 7) << 11) | ((bid >> 3) << 2) | (int)(threadIdx.x >> 6);
    const int lane = threadIdx.x & 63;
    const int b = m >> 10, l = m & 1023;

    const int t = lane & 31;
    const int idx = index[l*KNBR + t];
    const float s = scores[b*LL + idx] + mask[(size_t)m*KNBR + t];

    float mx = s;
    #pragma unroll
    for (int off = 16; off; off >>= 1) mx = fmaxf(mx, __shfl_xor(mx, off));
    const float e = __expf(s - mx);
    float sum = e;
    #pragma unroll
    for (int off = 16; off; off >>= 1) sum += __shfl_xor(sum, off);
    const float w = e / sum;

    const unsigned short* vbase = v + (size_t)(b << 10) * HD + lane*8;
    float a[8] = {};
    #pragma unroll 8
    for (int t2 = 0; t2 < KNBR; t2++) {
        const int   it = __shfl(idx, t2);
        const float wt = __shfl(w,   t2);
        const uint4 pv = *(const uint4*)(vbase + (size_t)it*HD);
        a[0] += wt * b2f_lo(pv.x); a[1] += wt * b2f_hi(pv.x);
        a[2] += wt * b2f_lo(pv.y); a[3] += wt * b2f_hi(pv.y);
        a[4] += wt * b2f_lo(pv.z); a[5] += wt * b2f_hi(pv.z);
        a[6] += wt * b2f_lo(pv.w); a[7] += wt * b2f_hi(pv.w);
    }
    uint4 o;
    o.x = (unsigned int)f2b(a[0]) | ((unsigned int)f2b(a[1]) << 16);
    o.y = (unsigned int)f2b(a[2]) | ((unsigned int)f2b(a[3]) << 16);
    o.z = (unsigned int)f2b(a[4]) | ((unsigned int)f2b(a[5]) << 16);
    o.w = (unsigned int)f2b(a[6]) | ((unsigned int)f2b(a[7]) << 16);
    *(uint4*)&attn[(size_t)m*HD + lane*8] = o;
}

// ------- dense GEMM + residual + LayerNorm fused -------
// 32 rows x 512 cols per block, 256 threads (4 waves, each a 128-col stripe).
// 512 blocks = 2 blocks/CU (LDS 69 KB). Counted-vmcnt pipeline (T3/T4):
// raw s_barrier + per-tile vmcnt(9/8) -- next tile's loads stay in flight
// across the barrier (no vmcnt(0) drain, unlike __syncthreads).
__global__ __launch_bounds__(256) void dense_ln(
    const unsigned short* __restrict__ A,    // attn_bf, MT x 512
    const unsigned short* __restrict__ W,    // Wd_bf, 512 x 512
    const float* __restrict__ bd, const unsigned short* __restrict__ res,
    const float* __restrict__ ln_g, const float* __restrict__ ln_b,
    float* __restrict__ out)
{
    __shared__ unsigned short As[2][32 * 32];    // 4 KB
    __shared__ unsigned short Bs[2][512 * 32];   // 64 KB
    __shared__ float rsum[4][32], rsq[4][32];    // 1 KB

    const int tid  = threadIdx.x;
    const int wave = tid >> 6, lane = tid & 63;
    const int row0 = blockIdx.x * 32;

    const int lrr = lane >> 2;
    const int cc  = lane & 3;
    const int fr   = lane & 15;
    const int quad = lane >> 4;

    f32x4 acc[2][8];
    #pragma unroll
    for (int i = 0; i < 2; i++)
        #pragma unroll
        for (int j = 0; j < 8; j++)
            acc[i][j] = (f32x4){0.f, 0.f, 0.f, 0.f};

    int a_off[2], b_off[8];
    #pragma unroll
    for (int i = 0; i < 2; i++) {
        const int m = i*16 + fr;
        a_off[i] = m*32 + ((quad ^ ((m >> 1) & 3)) << 3);
    }
    #pragma unroll
    for (int j = 0; j < 8; j++) {
        const int n = wave*128 + j*16 + fr;
        b_off[j] = n*32 + ((quad ^ ((n >> 1) & 3)) << 3);
    }

    // per-tile staging: waves 0,1 issue 9 loads (8 B + 1 A), waves 2,3 issue 8
    auto stage = [&](int bf, int k0) {
        #pragma unroll
        for (int t = 0; t < 8; t++) {
            const int n   = wave*128 + t*16 + lrr;
            const int gch = cc ^ ((n >> 1) & 3);
            const unsigned short* gw = &W[(size_t)n*HD + k0 + gch*8];
            __builtin_amdgcn_global_load_lds(
                (const __attribute__((address_space(1))) void*)gw,
                (__attribute__((address_space(3))) void*)&Bs[bf][(wave*128 + t*16)*32],
                16, 0, 0);
        }
        if (wave < 2) {
            const int mm  = wave*16 + lrr;
            const int gch = cc ^ ((mm >> 1) & 3);
            const unsigned short* ga = &A[(size_t)(row0 + mm)*HD + k0 + gch*8];
            __builtin_amdgcn_global_load_lds(
                (const __attribute__((address_space(1))) void*)ga,
                (__attribute__((address_space(3))) void*)&As[bf][(wave*16)*32],
                16, 0, 0);
        }
    };

    stage(0, 0);     // tile 0
    stage(1, 32);    // tile 1 (stays in flight across the first barrier)

    for (int s = 0; s < 16; ++s) {
        // wait only for tile s (this wave's own 9/8 loads of tile s+1 may remain)
        if (wave < 2) asm volatile("s_waitcnt vmcnt(9)" ::: "memory");
        else          asm volatile("s_waitcnt vmcnt(8)" ::: "memory");
        __builtin_amdgcn_s_barrier();          // tile s visible to all waves
        asm volatile("" ::: "memory");

        const int cur = s & 1;
        bf16x8 af[2], bfr[8];
        #pragma unroll
        for (int i = 0; i < 2; i++) af[i] = *(const bf16x8*)&As[cur][a_off[i]];
        #pragma unroll
        for (int j = 0; j < 8; j++) bfr[j] = *(const bf16x8*)&Bs[cur][b_off[j]];
        asm volatile("s_waitcnt lgkmcnt(0)" ::: "memory");
        __builtin_amdgcn_sched_barrier(0);     // rule #18: no MFMA hoist
        __builtin_amdgcn_s_barrier();          // all waves done reading buf[cur]

        if (s + 2 < 16) stage(cur, (s + 2) * 32);   // safe: buf[cur] free now

        __builtin_amdgcn_s_setprio(1);
        #pragma unroll
        for (int i = 0; i < 2; i++)
            #pragma unroll
            for (int j = 0; j < 8; j++)
                acc[i][j] = __builtin_amdgcn_mfma_f32_16x16x32_bf16(
                    af[i], bfr[j], acc[i][j], 0, 0, 0);
        __builtin_amdgcn_s_setprio(0);
    }
    __syncthreads();   // full drain once before epilogue

    float bdv[8], gv[8], lbv[8];
    #pragma unroll
    for (int j = 0; j < 8; j++) {
        const int col = wave*128 + j*16 + fr;
        bdv[j] = bd[col]; gv[j] = ln_g[col]; lbv[j] = ln_b[col];
    }

    #pragma unroll
    for (int i = 0; i < 2; i++) {
        #pragma unroll
        for (int r = 0; r < 4; r++) {
            const int lrow = i*16 + quad*4 + r;
            const size_t gr = (size_t)(row0 + lrow) * HD;
            float a1 = 0.f, a2 = 0.f;
            #pragma unroll
            for (int j = 0; j < 8; j++) {
                const int col = wave*128 + j*16 + fr;
                float val = acc[i][j][r] + bdv[j] + b2f(res[gr + col]);
                acc[i][j][r] = val;
                a1 += val; a2 += val*val;
            }
            #pragma unroll
            for (int off = 1; off < 16; off <<= 1) {
                a1 += __shfl_xor(a1, off);
                a2 += __shfl_xor(a2, off);
            }
            if (fr == 0) { rsum[wave][lrow] = a1; rsq[wave][lrow] = a2; }
        }
    }
    __syncthreads();

    #pragma unroll
    for (int i = 0; i < 2; i++) {
        #pragma unroll
        for (int r = 0; r < 4; r++) {
            const int lrow = i*16 + quad*4 + r;
            const float tot  = rsum[0][lrow] + rsum[1][lrow] + rsum[2][lrow] + rsum[3][lrow];
            const float tot2 = rsq[0][lrow]  + rsq[1][lrow]  + rsq[2][lrow]  + rsq[3][lrow];
            const float mu  = tot * (1.f/HD);
            const float var = tot2 * (1.f/HD) - mu*mu;
            const float inv = rsqrtf(var + 1e-12f);
            const size_t gr = (size_t)(row0 + lrow) * HD;
            #pragma unroll
            for (int j = 0; j < 8; j++) {
                const int col = wave*128 + j*16 + fr;
                out[gr + col] = (acc[i][j][r] - mu)*inv*gv[j] + lbv[j];
            }
        }
    }
}

extern "C" void kernel_launch(void* const* d_in, const int* in_sizes, int n_in,
                              void* d_out, int out_size, void* d_ws, size_t ws_size,
                              hipStream_t stream) {
    const float* user_emb = (const float*)d_in[0];
    const float* item_emb = (const float*)d_in[1];
    const float* mask     = (const float*)d_in[2];
    const int*   index    = (const int*)  d_in[3];
    const float* Wq = (const float*)d_in[4];  const float* bq = (const float*)d_in[5];
    const float* Wk = (const float*)d_in[6];  const float* bk = (const float*)d_in[7];
    const float* Wv = (const float*)d_in[8];  const float* bv = (const float*)d_in[9];
    const float* Wd = (const float*)d_in[10]; const float* bd = (const float*)d_in[11];
    const float* ln_g = (const float*)d_in[12];
    const float* ln_b = (const float*)d_in[13];

    float* out = (float*)d_out;

    char* p = (char*)d_ws;
    unsigned short* item_bf = (unsigned short*)p; p += (size_t)MT*HD*2;     // 16.8 MB
    unsigned short* v_bf    = (unsigned short*)p; p += (size_t)MT*HD*2;     // 16.8 MB
    unsigned short* attn_bf = (unsigned short*)p; p += (size_t)MT*HD*2;     // 16.8 MB
    unsigned short* Wv_bf   = (unsigned short*)p; p += (size_t)HD*HD*2;     // 0.5 MB
    unsigned short* Wd_bf   = (unsigned short*)p; p += (size_t)HD*HD*2;     // 0.5 MB
    float* q      = (float*)p; p += 16*HD*4;
    float* rbuf   = (float*)p; p += 16*HD*4;
    float* s0buf  = (float*)p; p += 16*4;
    float* scores = (float*)p; p += MT*4;

    // L1: convs + q projection
    prep<<<PB_CONV_I + PB_CONV_W + PB_Q, 256, 0, stream>>>(
        item_emb, Wv, Wd, user_emb, Wq, bq,
        item_bf, Wv_bf, Wd_bf, q);

    // L2: V GEMM + r matvec + s0
    gemm_v_r<<<656, 256, 0, stream>>>(item_bf, Wv_bf, bv, Wk, bk, q,
                                      v_bf, rbuf, s0buf);

    // L3: scores[m] = r[b].item_bf[m] + s0[b]
    gp_scores<<<MT/4, 256, 0, stream>>>(rbuf, s0buf, item_bf, scores);

    // L4: gather + softmax + PV -> attn_bf (XCD-swizzled)
    gp_attn<<<MT/4, 256, 0, stream>>>(scores, index, mask, v_bf, attn_bf);

    // L5: dense + residual + LN -> fp32 out (32-row blocks, 2/CU, counted vmcnt)
    dense_ln<<<MT/32, 256, 0, stream>>>(attn_bf, Wd_bf, bd, item_bf,
                                        ln_g, ln_b, out);
}

// Round 3
// 183.584 us; speedup vs baseline: 1.0052x; 1.0052x over previous
//
#include <hip/hip_runtime.h>
#include <math.h>

constexpr int HD   = 512;    // hidden
constexpr int LL   = 1024;   // SES*SEQ
constexpr int MT   = 16384;  // B*L rows
constexpr int KNBR = 32;     // K neighbors
constexpr float SCL = 0.04419417382415922f;  // 1/sqrt(512)

typedef __attribute__((ext_vector_type(8))) short  bf16x8;  // 8 bf16 = 4 VGPRs
typedef __attribute__((ext_vector_type(4))) float  f32x4;

__device__ inline float b2f(unsigned short u) {
    union { unsigned int i; float f; } v; v.i = (unsigned int)u << 16; return v.f;
}
__device__ inline float b2f_lo(unsigned int u) {
    union { unsigned int i; float f; } v; v.i = u << 16; return v.f;
}
__device__ inline float b2f_hi(unsigned int u) {
    union { unsigned int i; float f; } v; v.i = u & 0xffff0000u; return v.f;
}
__device__ inline unsigned short f2b(float x) {
    union { float f; unsigned int u; } v; v.f = x;
    unsigned int r = v.u + 0x7fff + ((v.u >> 16) & 1);
    return (unsigned short)(r >> 16);
}

// ================= prep: convs + q-projection, one launch ==================
constexpr int PB_CONV_I = 8192;
constexpr int PB_CONV_W = 512;
constexpr int PB_Q      = 2048;

__global__ __launch_bounds__(256) void prep(
    const float* __restrict__ item, const float* __restrict__ Wv,
    const float* __restrict__ Wd, const float* __restrict__ u,
    const float* __restrict__ Wq, const float* __restrict__ bq,
    unsigned short* __restrict__ item_bf, unsigned short* __restrict__ Wv_bf,
    unsigned short* __restrict__ Wd_bf, float* __restrict__ q)
{
    const int blk = blockIdx.x, tid = threadIdx.x;

    if (blk < PB_CONV_I) {
        const int i = blk * 1024 + tid * 4;
        float4 v = *(const float4*)&item[i];
        ushort4 o;
        o.x = f2b(v.x); o.y = f2b(v.y); o.z = f2b(v.z); o.w = f2b(v.w);
        *(ushort4*)&item_bf[i] = o;
        return;
    }
    if (blk < PB_CONV_I + PB_CONV_W) {
        const int n = HD*HD;
        const int i = (blk - PB_CONV_I) * 1024 + tid * 4;
        const float* s; unsigned short* d; int off;
        if (i < n) { s = Wv; d = Wv_bf; off = i; }
        else       { s = Wd; d = Wd_bf; off = i - n; }
        float4 v = *(const float4*)&s[off];
        ushort4 o;
        o.x = f2b(v.x); o.y = f2b(v.y); o.z = f2b(v.z); o.w = f2b(v.w);
        *(ushort4*)&d[off] = o;
        return;
    }
    {   // q[b][h], one wave per (b,h)
        const int wid  = (blk - PB_CONV_I - PB_CONV_W) * 4 + (tid >> 6);
        const int lane = tid & 63;
        const int b = wid >> 9, h = wid & 511;
        const float* ur = &u[b*HD + lane*8];
        const float* wr = &Wq[(size_t)h*HD + lane*8];
        const float4 u0 = *(const float4*)ur, u1 = *(const float4*)(ur+4);
        const float4 w0 = *(const float4*)wr, w1 = *(const float4*)(wr+4);
        float acc = u0.x*w0.x + u0.y*w0.y + u0.z*w0.z + u0.w*w0.w
                  + u1.x*w1.x + u1.y*w1.y + u1.z*w1.z + u1.w*w1.w;
        #pragma unroll
        for (int off = 32; off; off >>= 1) acc += __shfl_down(acc, off);
        if (lane == 0) q[b*HD + h] = acc + bq[h];
    }
}

// ======= gemm_v_r: V GEMM + r matvec + s0, one launch =======
// GEMM section: counted-vmcnt raw-barrier pipeline (T3/T4), 4 loads/wave/tile,
// steady-state wait vmcnt(4); final iteration peeled with vmcnt(0) (race fix).
__global__ __launch_bounds__(256) void gemm_v_r(
    const unsigned short* __restrict__ A, const unsigned short* __restrict__ W,
    const float* __restrict__ bv, const float* __restrict__ Wk,
    const float* __restrict__ bk, const float* __restrict__ q,
    unsigned short* __restrict__ v_bf, float* __restrict__ rbuf,
    float* __restrict__ s0buf)
{
    __shared__ unsigned short As[2][128 * 32];   // 2 x 8 KB
    __shared__ unsigned short Bs[2][128 * 32];   // 2 x 8 KB

    const int blk = blockIdx.x;
    const int tid = threadIdx.x;

    if (blk >= 512) {
        if (blk < 640) {
            __shared__ float red[4][64];
            const int rblk = blk - 512;
            const int b = rblk >> 3, c0 = (rblk & 7) * 64;
            const int cl = tid & 63, hg = tid >> 6;
            const float* qb = &q[b*HD];
            const float* wb = &Wk[(size_t)hg*128*HD + c0 + cl];
            float acc = 0.f;
            #pragma unroll 8
            for (int h = 0; h < 128; h++)
                acc += qb[hg*128 + h] * wb[(size_t)h*HD];
            red[hg][cl] = acc;
            __syncthreads();
            if (tid < 64)
                rbuf[b*HD + c0 + tid] = SCL *
                    (red[0][tid] + red[1][tid] + red[2][tid] + red[3][tid]);
        } else {
            __shared__ float sp[4];
            const int b = blk - 640;
            float p = q[b*HD + tid]*bk[tid] + q[b*HD + tid + 256]*bk[tid + 256];
            #pragma unroll
            for (int off = 32; off; off >>= 1) p += __shfl_down(p, off);
            if ((tid & 63) == 0) sp[tid >> 6] = p;
            __syncthreads();
            if (tid == 0) s0buf[b] = (sp[0] + sp[1] + sp[2] + sp[3]) * SCL;
        }
        return;
    }

    // ---- V GEMM tile ----
    const int rowb = (blk & 7) | ((blk >> 5) << 3);   // 0..127
    const int colb = (blk >> 3) & 3;                  // 0..3
    const int row0 = rowb * 128;
    const int col0 = colb * 128;

    const int wave = tid >> 6, lane = tid & 63;
    const int wm = (wave >> 1) * 64;
    const int wn = (wave & 1)  * 64;

    const int lrr = lane >> 2;
    const int cc  = lane & 3;
    int st_row[2], st_gchunk[2];
    #pragma unroll
    for (int t = 0; t < 2; t++) {
        const int m = wave*32 + t*16 + lrr;
        st_row[t]    = m;
        st_gchunk[t] = cc ^ ((m >> 1) & 3);
    }

    const int fr   = lane & 15;
    const int quad = lane >> 4;

    f32x4 acc[4][4];
    #pragma unroll
    for (int i = 0; i < 4; i++)
        #pragma unroll
        for (int j = 0; j < 4; j++)
            acc[i][j] = (f32x4){0.f, 0.f, 0.f, 0.f};

    int a_off[4], b_off[4];
    #pragma unroll
    for (int i = 0; i < 4; i++) {
        const int m = wm + i*16 + fr;
        a_off[i] = m*32 + ((quad ^ ((m >> 1) & 3)) << 3);
        const int n = wn + i*16 + fr;
        b_off[i] = n*32 + ((quad ^ ((n >> 1) & 3)) << 3);
    }

    auto stage = [&](int bf, int k0) {
        #pragma unroll
        for (int t = 0; t < 2; t++) {
            const int m = st_row[t];
            const unsigned short* ga = &A[(size_t)(row0 + m)*HD + k0 + st_gchunk[t]*8];
            __builtin_amdgcn_global_load_lds(
                (const __attribute__((address_space(1))) void*)ga,
                (__attribute__((address_space(3))) void*)&As[bf][(wave*32 + t*16)*32],
                16, 0, 0);
            const unsigned short* gw = &W[(size_t)(col0 + m)*HD + k0 + st_gchunk[t]*8];
            __builtin_amdgcn_global_load_lds(
                (const __attribute__((address_space(1))) void*)gw,
                (__attribute__((address_space(3))) void*)&Bs[bf][(wave*32 + t*16)*32],
                16, 0, 0);
        }
    };

    stage(0, 0);     // tile 0
    stage(1, 32);    // tile 1 stays in flight across the barrier

    for (int s = 0; s < 15; ++s) {
        // wait for tile s only (tile s+1's 4 loads remain in flight)
        asm volatile("s_waitcnt vmcnt(4)" ::: "memory");
        __builtin_amdgcn_s_barrier();          // tile s visible to all waves
        asm volatile("" ::: "memory");

        const int cur = s & 1;
        bf16x8 af[4], bfr[4];
        #pragma unroll
        for (int i = 0; i < 4; i++) {
            af[i]  = *(const bf16x8*)&As[cur][a_off[i]];
            bfr[i] = *(const bf16x8*)&Bs[cur][b_off[i]];
        }
        asm volatile("s_waitcnt lgkmcnt(0)" ::: "memory");
        __builtin_amdgcn_sched_barrier(0);     // rule #18
        __builtin_amdgcn_s_barrier();          // all waves done reading buf[cur]

        if (s + 2 < 16) stage(cur, (s + 2) * 32);

        __builtin_amdgcn_s_setprio(1);
        #pragma unroll
        for (int i = 0; i < 4; i++)
            #pragma unroll
            for (int j = 0; j < 4; j++)
                acc[i][j] = __builtin_amdgcn_mfma_f32_16x16x32_bf16(
                    af[i], bfr[j], acc[i][j], 0, 0, 0);
        __builtin_amdgcn_s_setprio(0);
    }
    {   // final K-step (s=15): MUST drain vmcnt fully (tile 15 is the only
        // one outstanding -> a counted wait would pass before it lands)
        asm volatile("s_waitcnt vmcnt(0)" ::: "memory");
        __builtin_amdgcn_s_barrier();
        asm volatile("" ::: "memory");
        bf16x8 af[4], bfr[4];
        #pragma unroll
        for (int i = 0; i < 4; i++) {
            af[i]  = *(const bf16x8*)&As[1][a_off[i]];
            bfr[i] = *(const bf16x8*)&Bs[1][b_off[i]];
        }
        asm volatile("s_waitcnt lgkmcnt(0)" ::: "memory");
        __builtin_amdgcn_sched_barrier(0);
        #pragma unroll
        for (int i = 0; i < 4; i++)
            #pragma unroll
            for (int j = 0; j < 4; j++)
                acc[i][j] = __builtin_amdgcn_mfma_f32_16x16x32_bf16(
                    af[i], bfr[j], acc[i][j], 0, 0, 0);
    }

    #pragma unroll
    for (int j = 0; j < 4; j++) {
        const int col = col0 + wn + j*16 + fr;
        const float bb = bv[col];
        #pragma unroll
        for (int i = 0; i < 4; i++) {
            #pragma unroll
            for (int r = 0; r < 4; r++) {
                const int row = row0 + wm + i*16 + quad*4 + r;
                v_bf[(size_t)row*HD + col] = f2b(acc[i][j][r] + bb);
            }
        }
    }
}

// ------- scores[m] = r[b] . item_bf[m] + s0[b], one wave per row -------
__global__ __launch_bounds__(256) void gp_scores(
    const float* __restrict__ rbuf, const float* __restrict__ s0buf,
    const unsigned short* __restrict__ item_bf, float* __restrict__ scores)
{
    const int m = blockIdx.x * 4 + (threadIdx.x >> 6);
    const int lane = threadIdx.x & 63;
    const int b = m >> 10;
    const unsigned short* ir = &item_bf[(size_t)m*HD + lane*8];
    const uint4 iv = *(const uint4*)ir;
    const float* rr = &rbuf[b*HD + lane*8];
    const float4 r0 = *(const float4*)rr;
    const float4 r1 = *(const float4*)(rr + 4);
    float acc = r0.x*b2f_lo(iv.x) + r0.y*b2f_hi(iv.x)
              + r0.z*b2f_lo(iv.y) + r0.w*b2f_hi(iv.y)
              + r1.x*b2f_lo(iv.z) + r1.y*b2f_hi(iv.z)
              + r1.z*b2f_lo(iv.w) + r1.w*b2f_hi(iv.w);
    #pragma unroll
    for (int off = 32; off; off >>= 1) acc += __shfl_down(acc, off);
    if (lane == 0) scores[m] = acc + s0buf[b];
}

// ----- gather + softmax + weighted sum of v: one wave per row -----
// (it, wt) broadcast via v_readlane (SGPR), so the gather is a saddr-form
// global_load_dwordx4 with a single per-lane voffset and the FMAs take wt
// as the SGPR operand -- roughly halves VALU vs ds_bpermute __shfl.
__global__ __launch_bounds__(256) void gp_attn(
    const float* __restrict__ scores, const int* __restrict__ index,
    const float* __restrict__ mask, const unsigned short* __restrict__ v,
    unsigned short* __restrict__ attn)
{
    const int bid = blockIdx.x;
    const int m = ((bid & 7) << 11) | ((bid >> 3) << 2) | (int)(threadIdx.x >> 6);
    const int lane = threadIdx.x & 63;
    const int b = m >> 10, l = m & 1023;

    const int t = lane & 31;
    const int idx = index[l*KNBR + t];
    const float s = scores[b*LL + idx] + mask[(size_t)m*KNBR + t];

    float mx = s;
    #pragma unroll
    for (int off = 16; off; off >>= 1) mx = fmaxf(mx, __shfl_xor(mx, off));
    const float e = __expf(s - mx);
    float sum = e;
    #pragma unroll
    for (int off = 16; off; off >>= 1) sum += __shfl_xor(sum, off);
    const float w = e / sum;

    const unsigned short* vb = v + (size_t)(b << 10) * HD;
    const int loff = lane * 8;
    float a[8] = {};
    #pragma unroll 8
    for (int t2 = 0; t2 < KNBR; t2++) {
        const int   it = __builtin_amdgcn_readlane(idx, t2);              // SGPR
        const float wt = __int_as_float(
            __builtin_amdgcn_readlane(__float_as_int(w), t2));            // SGPR
        const uint4 pv = *(const uint4*)(vb + (size_t)it*HD + loff);
        a[0] += wt * b2f_lo(pv.x); a[1] += wt * b2f_hi(pv.x);
        a[2] += wt * b2f_lo(pv.y); a[3] += wt * b2f_hi(pv.y);
        a[4] += wt * b2f_lo(pv.z); a[5] += wt * b2f_hi(pv.z);
        a[6] += wt * b2f_lo(pv.w); a[7] += wt * b2f_hi(pv.w);
    }
    uint4 o;
    o.x = (unsigned int)f2b(a[0]) | ((unsigned int)f2b(a[1]) << 16);
    o.y = (unsigned int)f2b(a[2]) | ((unsigned int)f2b(a[3]) << 16);
    o.z = (unsigned int)f2b(a[4]) | ((unsigned int)f2b(a[5]) << 16);
    o.w = (unsigned int)f2b(a[6]) | ((unsigned int)f2b(a[7]) << 16);
    *(uint4*)&attn[(size_t)m*HD + lane*8] = o;
}

// ------- dense GEMM + residual + LayerNorm fused -------
// 32 rows x 512 cols per block, 256 threads (4 waves, 128-col stripes).
// 512 blocks = 2 blocks/CU. Counted-vmcnt pipeline; final iteration peeled
// with vmcnt(0) (race fix: counted wait is a no-op on the last tile).
__global__ __launch_bounds__(256) void dense_ln(
    const unsigned short* __restrict__ A,    // attn_bf, MT x 512
    const unsigned short* __restrict__ W,    // Wd_bf, 512 x 512
    const float* __restrict__ bd, const unsigned short* __restrict__ res,
    const float* __restrict__ ln_g, const float* __restrict__ ln_b,
    float* __restrict__ out)
{
    __shared__ unsigned short As[2][32 * 32];    // 4 KB
    __shared__ unsigned short Bs[2][512 * 32];   // 64 KB
    __shared__ float rsum[4][32], rsq[4][32];    // 1 KB

    const int tid  = threadIdx.x;
    const int wave = tid >> 6, lane = tid & 63;
    const int row0 = blockIdx.x * 32;

    const int lrr = lane >> 2;
    const int cc  = lane & 3;
    const int fr   = lane & 15;
    const int quad = lane >> 4;

    f32x4 acc[2][8];
    #pragma unroll
    for (int i = 0; i < 2; i++)
        #pragma unroll
        for (int j = 0; j < 8; j++)
            acc[i][j] = (f32x4){0.f, 0.f, 0.f, 0.f};

    int a_off[2], b_off[8];
    #pragma unroll
    for (int i = 0; i < 2; i++) {
        const int m = i*16 + fr;
        a_off[i] = m*32 + ((quad ^ ((m >> 1) & 3)) << 3);
    }
    #pragma unroll
    for (int j = 0; j < 8; j++) {
        const int n = wave*128 + j*16 + fr;
        b_off[j] = n*32 + ((quad ^ ((n >> 1) & 3)) << 3);
    }

    // waves 0,1 issue 9 loads/tile (8 B + 1 A); waves 2,3 issue 8
    auto stage = [&](int bf, int k0) {
        #pragma unroll
        for (int t = 0; t < 8; t++) {
            const int n   = wave*128 + t*16 + lrr;
            const int gch = cc ^ ((n >> 1) & 3);
            const unsigned short* gw = &W[(size_t)n*HD + k0 + gch*8];
            __builtin_amdgcn_global_load_lds(
                (const __attribute__((address_space(1))) void*)gw,
                (__attribute__((address_space(3))) void*)&Bs[bf][(wave*128 + t*16)*32],
                16, 0, 0);
        }
        if (wave < 2) {
            const int mm  = wave*16 + lrr;
            const int gch = cc ^ ((mm >> 1) & 3);
            const unsigned short* ga = &A[(size_t)(row0 + mm)*HD + k0 + gch*8];
            __builtin_amdgcn_global_load_lds(
                (const __attribute__((address_space(1))) void*)ga,
                (__attribute__((address_space(3))) void*)&As[bf][(wave*16)*32],
                16, 0, 0);
        }
    };

    stage(0, 0);     // tile 0
    stage(1, 32);    // tile 1 (in flight across the first barrier)

    for (int s = 0; s < 15; ++s) {
        if (wave < 2) asm volatile("s_waitcnt vmcnt(9)" ::: "memory");
        else          asm volatile("s_waitcnt vmcnt(8)" ::: "memory");
        __builtin_amdgcn_s_barrier();          // tile s visible to all waves
        asm volatile("" ::: "memory");

        const int cur = s & 1;
        bf16x8 af[2], bfr[8];
        #pragma unroll
        for (int i = 0; i < 2; i++) af[i] = *(const bf16x8*)&As[cur][a_off[i]];
        #pragma unroll
        for (int j = 0; j < 8; j++) bfr[j] = *(const bf16x8*)&Bs[cur][b_off[j]];
        asm volatile("s_waitcnt lgkmcnt(0)" ::: "memory");
        __builtin_amdgcn_sched_barrier(0);     // rule #18: no MFMA hoist
        __builtin_amdgcn_s_barrier();          // all waves done reading buf[cur]

        if (s + 2 < 16) stage(cur, (s + 2) * 32);

        __builtin_amdgcn_s_setprio(1);
        #pragma unroll
        for (int i = 0; i < 2; i++)
            #pragma unroll
            for (int j = 0; j < 8; j++)
                acc[i][j] = __builtin_amdgcn_mfma_f32_16x16x32_bf16(
                    af[i], bfr[j], acc[i][j], 0, 0, 0);
        __builtin_amdgcn_s_setprio(0);
    }
    {   // final K-step (s=15): full drain (race fix)
        asm volatile("s_waitcnt vmcnt(0)" ::: "memory");
        __builtin_amdgcn_s_barrier();
        asm volatile("" ::: "memory");
        bf16x8 af[2], bfr[8];
        #pragma unroll
        for (int i = 0; i < 2; i++) af[i] = *(const bf16x8*)&As[1][a_off[i]];
        #pragma unroll
        for (int j = 0; j < 8; j++) bfr[j] = *(const bf16x8*)&Bs[1][b_off[j]];
        asm volatile("s_waitcnt lgkmcnt(0)" ::: "memory");
        __builtin_amdgcn_sched_barrier(0);
        #pragma unroll
        for (int i = 0; i < 2; i++)
            #pragma unroll
            for (int j = 0; j < 8; j++)
                acc[i][j] = __builtin_amdgcn_mfma_f32_16x16x32_bf16(
                    af[i], bfr[j], acc[i][j], 0, 0, 0);
    }
    __syncthreads();

    float bdv[8], gv[8], lbv[8];
    #pragma unroll
    for (int j = 0; j < 8; j++) {
        const int col = wave*128 + j*16 + fr;
        bdv[j] = bd[col]; gv[j] = ln_g[col]; lbv[j] = ln_b[col];
    }

    #pragma unroll
    for (int i = 0; i < 2; i++) {
        #pragma unroll
        for (int r = 0; r < 4; r++) {
            const int lrow = i*16 + quad*4 + r;
            const size_t gr = (size_t)(row0 + lrow) * HD;
            float a1 = 0.f, a2 = 0.f;
            #pragma unroll
            for (int j = 0; j < 8; j++) {
                const int col = wave*128 + j*16 + fr;
                float val = acc[i][j][r] + bdv[j] + b2f(res[gr + col]);
                acc[i][j][r] = val;
                a1 += val; a2 += val*val;
            }
            #pragma unroll
            for (int off = 1; off < 16; off <<= 1) {
                a1 += __shfl_xor(a1, off);
                a2 += __shfl_xor(a2, off);
            }
            if (fr == 0) { rsum[wave][lrow] = a1; rsq[wave][lrow] = a2; }
        }
    }
    __syncthreads();

    #pragma unroll
    for (int i = 0; i < 2; i++) {
        #pragma unroll
        for (int r = 0; r < 4; r++) {
            const int lrow = i*16 + quad*4 + r;
            const float tot  = rsum[0][lrow] + rsum[1][lrow] + rsum[2][lrow] + rsum[3][lrow];
            const float tot2 = rsq[0][lrow]  + rsq[1][lrow]  + rsq[2][lrow]  + rsq[3][lrow];
            const float mu  = tot * (1.f/HD);
            const float var = tot2 * (1.f/HD) - mu*mu;
            const float inv = rsqrtf(var + 1e-12f);
            const size_t gr = (size_t)(row0 + lrow) * HD;
            #pragma unroll
            for (int j = 0; j < 8; j++) {
                const int col = wave*128 + j*16 + fr;
                out[gr + col] = (acc[i][j][r] - mu)*inv*gv[j] + lbv[j];
            }
        }
    }
}

extern "C" void kernel_launch(void* const* d_in, const int* in_sizes, int n_in,
                              void* d_out, int out_size, void* d_ws, size_t ws_size,
                              hipStream_t stream) {
    const float* user_emb = (const float*)d_in[0];
    const float* item_emb = (const float*)d_in[1];
    const float* mask     = (const float*)d_in[2];
    const int*   index    = (const int*)  d_in[3];
    const float* Wq = (const float*)d_in[4];  const float* bq = (const float*)d_in[5];
    const float* Wk = (const float*)d_in[6];  const float* bk = (const float*)d_in[7];
    const float* Wv = (const float*)d_in[8];  const float* bv = (const float*)d_in[9];
    const float* Wd = (const float*)d_in[10]; const float* bd = (const float*)d_in[11];
    const float* ln_g = (const float*)d_in[12];
    const float* ln_b = (const float*)d_in[13];

    float* out = (float*)d_out;

    char* p = (char*)d_ws;
    unsigned short* item_bf = (unsigned short*)p; p += (size_t)MT*HD*2;     // 16.8 MB
    unsigned short* v_bf    = (unsigned short*)p; p += (size_t)MT*HD*2;     // 16.8 MB
    unsigned short* attn_bf = (unsigned short*)p; p += (size_t)MT*HD*2;     // 16.8 MB
    unsigned short* Wv_bf   = (unsigned short*)p; p += (size_t)HD*HD*2;     // 0.5 MB
    unsigned short* Wd_bf   = (unsigned short*)p; p += (size_t)HD*HD*2;     // 0.5 MB
    float* q      = (float*)p; p += 16*HD*4;
    float* rbuf   = (float*)p; p += 16*HD*4;
    float* s0buf  = (float*)p; p += 16*4;
    float* scores = (float*)p; p += MT*4;

    // L1: convs + q projection
    prep<<<PB_CONV_I + PB_CONV_W + PB_Q, 256, 0, stream>>>(
        item_emb, Wv, Wd, user_emb, Wq, bq,
        item_bf, Wv_bf, Wd_bf, q);

    // L2: V GEMM + r matvec + s0 (counted-vmcnt pipeline)
    gemm_v_r<<<656, 256, 0, stream>>>(item_bf, Wv_bf, bv, Wk, bk, q,
                                      v_bf, rbuf, s0buf);

    // L3: scores[m] = r[b].item_bf[m] + s0[b]
    gp_scores<<<MT/4, 256, 0, stream>>>(rbuf, s0buf, item_bf, scores);

    // L4: gather + softmax + PV -> attn_bf (XCD-swizzled, readlane broadcast)
    gp_attn<<<MT/4, 256, 0, stream>>>(scores, index, mask, v_bf, attn_bf);

    // L5: dense + residual + LN -> fp32 out (counted vmcnt, race-fixed)
    dense_ln<<<MT/32, 256, 0, stream>>>(attn_bf, Wd_bf, bd, item_bf,
                                        ln_g, ln_b, out);
}

// Round 4
// 178.518 us; speedup vs baseline: 1.0338x; 1.0284x over previous
//
#include <hip/hip_runtime.h>
#include <math.h>

constexpr int HD   = 512;    // hidden
constexpr int LL   = 1024;   // SES*SEQ
constexpr int MT   = 16384;  // B*L rows
constexpr int KNBR = 32;     // K neighbors
constexpr float SCL = 0.04419417382415922f;  // 1/sqrt(512)

typedef __attribute__((ext_vector_type(8))) short  bf16x8;  // 8 bf16 = 4 VGPRs
typedef __attribute__((ext_vector_type(4))) float  f32x4;

__device__ inline float b2f(unsigned short u) {
    union { unsigned int i; float f; } v; v.i = (unsigned int)u << 16; return v.f;
}
__device__ inline float b2f_lo(unsigned int u) {
    union { unsigned int i; float f; } v; v.i = u << 16; return v.f;
}
__device__ inline float b2f_hi(unsigned int u) {
    union { unsigned int i; float f; } v; v.i = u & 0xffff0000u; return v.f;
}
__device__ inline unsigned short f2b(float x) {
    union { float f; unsigned int u; } v; v.f = x;
    unsigned int r = v.u + 0x7fff + ((v.u >> 16) & 1);
    return (unsigned short)(r >> 16);
}

// ================= prep: convs + q-projection, one launch ==================
// Weights converted to K-TILED layout: panel kt holds [n][kk] contiguous
// (32 KB/panel) so GEMM staging of one K-step is a contiguous stream.
// item additionally emitted K-tiled (item_kt) for the V-GEMM A operand.
constexpr int PB_CONV_I = 8192;
constexpr int PB_CONV_W = 512;
constexpr int PB_Q      = 2048;

__global__ __launch_bounds__(256) void prep(
    const float* __restrict__ item, const float* __restrict__ Wv,
    const float* __restrict__ Wd, const float* __restrict__ u,
    const float* __restrict__ Wq, const float* __restrict__ bq,
    unsigned short* __restrict__ item_bf, unsigned short* __restrict__ item_kt,
    unsigned short* __restrict__ Wv_bf, unsigned short* __restrict__ Wd_bf,
    float* __restrict__ q)
{
    const int blk = blockIdx.x, tid = threadIdx.x;

    if (blk < PB_CONV_I) {
        const int i = blk * 1024 + tid * 4;
        float4 v = *(const float4*)&item[i];
        ushort4 o;
        o.x = f2b(v.x); o.y = f2b(v.y); o.z = f2b(v.z); o.w = f2b(v.w);
        *(ushort4*)&item_bf[i] = o;                       // row-major copy
        const int m = i >> 9, k = i & 511;                // K-tiled copy
        *(ushort4*)&item_kt[((size_t)(k >> 5) * MT + m) * 32 + (k & 31)] = o;
        return;
    }
    if (blk < PB_CONV_I + PB_CONV_W) {
        const int n = HD*HD;
        const int i = (blk - PB_CONV_I) * 1024 + tid * 4;
        const float* s; unsigned short* d; int off;
        if (i < n) { s = Wv; d = Wv_bf; off = i; }
        else       { s = Wd; d = Wd_bf; off = i - n; }
        float4 v = *(const float4*)&s[off];
        ushort4 o;
        o.x = f2b(v.x); o.y = f2b(v.y); o.z = f2b(v.z); o.w = f2b(v.w);
        const int nr = off >> 9, k = off & 511;           // K-tiled store
        *(ushort4*)&d[((k >> 5) * 512 + nr) * 32 + (k & 31)] = o;
        return;
    }
    {   // q[b][h], one wave per (b,h)
        const int wid  = (blk - PB_CONV_I - PB_CONV_W) * 4 + (tid >> 6);
        const int lane = tid & 63;
        const int b = wid >> 9, h = wid & 511;
        const float* ur = &u[b*HD + lane*8];
        const float* wr = &Wq[(size_t)h*HD + lane*8];
        const float4 u0 = *(const float4*)ur, u1 = *(const float4*)(ur+4);
        const float4 w0 = *(const float4*)wr, w1 = *(const float4*)(wr+4);
        float acc = u0.x*w0.x + u0.y*w0.y + u0.z*w0.z + u0.w*w0.w
                  + u1.x*w1.x + u1.y*w1.y + u1.z*w1.z + u1.w*w1.w;
        #pragma unroll
        for (int off = 32; off; off >>= 1) acc += __shfl_down(acc, off);
        if (lane == 0) q[b*HD + h] = acc + bq[h];
    }
}

// ======= gemm_v_r: V GEMM + r matvec + s0, one launch =======
// A from item_kt (K-tiled), W from Wv_bf (K-tiled): staging is contiguous.
// Counted-vmcnt raw-barrier pipeline; final step peeled with vmcnt(0).
__global__ __launch_bounds__(256) void gemm_v_r(
    const unsigned short* __restrict__ Akt, const unsigned short* __restrict__ Wt,
    const float* __restrict__ bv, const float* __restrict__ Wk,
    const float* __restrict__ bk, const float* __restrict__ q,
    unsigned short* __restrict__ v_bf, float* __restrict__ rbuf,
    float* __restrict__ s0buf)
{
    __shared__ unsigned short As[2][128 * 32];   // 2 x 8 KB
    __shared__ unsigned short Bs[2][128 * 32];   // 2 x 8 KB

    const int blk = blockIdx.x;
    const int tid = threadIdx.x;

    if (blk >= 512) {
        if (blk < 640) {
            __shared__ float red[4][64];
            const int rblk = blk - 512;
            const int b = rblk >> 3, c0 = (rblk & 7) * 64;
            const int cl = tid & 63, hg = tid >> 6;
            const float* qb = &q[b*HD];
            const float* wb = &Wk[(size_t)hg*128*HD + c0 + cl];
            float acc = 0.f;
            #pragma unroll 8
            for (int h = 0; h < 128; h++)
                acc += qb[hg*128 + h] * wb[(size_t)h*HD];
            red[hg][cl] = acc;
            __syncthreads();
            if (tid < 64)
                rbuf[b*HD + c0 + tid] = SCL *
                    (red[0][tid] + red[1][tid] + red[2][tid] + red[3][tid]);
        } else {
            __shared__ float sp[4];
            const int b = blk - 640;
            float p = q[b*HD + tid]*bk[tid] + q[b*HD + tid + 256]*bk[tid + 256];
            #pragma unroll
            for (int off = 32; off; off >>= 1) p += __shfl_down(p, off);
            if ((tid & 63) == 0) sp[tid >> 6] = p;
            __syncthreads();
            if (tid == 0) s0buf[b] = (sp[0] + sp[1] + sp[2] + sp[3]) * SCL;
        }
        return;
    }

    // ---- V GEMM tile ----
    const int rowb = (blk & 7) | ((blk >> 5) << 3);   // 0..127
    const int colb = (blk >> 3) & 3;                  // 0..3
    const int row0 = rowb * 128;
    const int col0 = colb * 128;

    const int wave = tid >> 6, lane = tid & 63;
    const int wm = (wave >> 1) * 64;
    const int wn = (wave & 1)  * 64;

    const int lrr = lane >> 2;
    const int cc  = lane & 3;
    int st_row[2], st_gchunk[2];
    #pragma unroll
    for (int t = 0; t < 2; t++) {
        const int m = wave*32 + t*16 + lrr;
        st_row[t]    = m;
        st_gchunk[t] = cc ^ ((m >> 1) & 3);
    }

    const int fr   = lane & 15;
    const int quad = lane >> 4;

    f32x4 acc[4][4];
    #pragma unroll
    for (int i = 0; i < 4; i++)
        #pragma unroll
        for (int j = 0; j < 4; j++)
            acc[i][j] = (f32x4){0.f, 0.f, 0.f, 0.f};

    int a_off[4], b_off[4];
    #pragma unroll
    for (int i = 0; i < 4; i++) {
        const int m = wm + i*16 + fr;
        a_off[i] = m*32 + ((quad ^ ((m >> 1) & 3)) << 3);
        const int n = wn + i*16 + fr;
        b_off[i] = n*32 + ((quad ^ ((n >> 1) & 3)) << 3);
    }

    // stage K-tile kt: contiguous 32 KB panels (coalesced per wave-group)
    auto stage = [&](int bf, int kt) {
        #pragma unroll
        for (int t = 0; t < 2; t++) {
            const int m = st_row[t];
            const unsigned short* ga =
                &Akt[((size_t)kt*MT + row0 + m)*32 + st_gchunk[t]*8];
            __builtin_amdgcn_global_load_lds(
                (const __attribute__((address_space(1))) void*)ga,
                (__attribute__((address_space(3))) void*)&As[bf][(wave*32 + t*16)*32],
                16, 0, 0);
            const unsigned short* gw =
                &Wt[((size_t)kt*512 + col0 + m)*32 + st_gchunk[t]*8];
            __builtin_amdgcn_global_load_lds(
                (const __attribute__((address_space(1))) void*)gw,
                (__attribute__((address_space(3))) void*)&Bs[bf][(wave*32 + t*16)*32],
                16, 0, 0);
        }
    };

    stage(0, 0);     // tile 0
    stage(1, 1);     // tile 1 stays in flight across the barrier

    for (int s = 0; s < 15; ++s) {
        asm volatile("s_waitcnt vmcnt(4)" ::: "memory");
        __builtin_amdgcn_s_barrier();
        asm volatile("" ::: "memory");

        const int cur = s & 1;
        bf16x8 af[4], bfr[4];
        #pragma unroll
        for (int i = 0; i < 4; i++) {
            af[i]  = *(const bf16x8*)&As[cur][a_off[i]];
            bfr[i] = *(const bf16x8*)&Bs[cur][b_off[i]];
        }
        asm volatile("s_waitcnt lgkmcnt(0)" ::: "memory");
        __builtin_amdgcn_sched_barrier(0);     // rule #18
        __builtin_amdgcn_s_barrier();

        if (s + 2 < 16) stage(cur, s + 2);

        __builtin_amdgcn_s_setprio(1);
        #pragma unroll
        for (int i = 0; i < 4; i++)
            #pragma unroll
            for (int j = 0; j < 4; j++)
                acc[i][j] = __builtin_amdgcn_mfma_f32_16x16x32_bf16(
                    af[i], bfr[j], acc[i][j], 0, 0, 0);
        __builtin_amdgcn_s_setprio(0);
    }
    {   // final K-step (s=15): full drain (counted wait would not cover it)
        asm volatile("s_waitcnt vmcnt(0)" ::: "memory");
        __builtin_amdgcn_s_barrier();
        asm volatile("" ::: "memory");
        bf16x8 af[4], bfr[4];
        #pragma unroll
        for (int i = 0; i < 4; i++) {
            af[i]  = *(const bf16x8*)&As[1][a_off[i]];
            bfr[i] = *(const bf16x8*)&Bs[1][b_off[i]];
        }
        asm volatile("s_waitcnt lgkmcnt(0)" ::: "memory");
        __builtin_amdgcn_sched_barrier(0);
        #pragma unroll
        for (int i = 0; i < 4; i++)
            #pragma unroll
            for (int j = 0; j < 4; j++)
                acc[i][j] = __builtin_amdgcn_mfma_f32_16x16x32_bf16(
                    af[i], bfr[j], acc[i][j], 0, 0, 0);
    }

    #pragma unroll
    for (int j = 0; j < 4; j++) {
        const int col = col0 + wn + j*16 + fr;
        const float bb = bv[col];
        #pragma unroll
        for (int i = 0; i < 4; i++) {
            #pragma unroll
            for (int r = 0; r < 4; r++) {
                const int row = row0 + wm + i*16 + quad*4 + r;
                v_bf[(size_t)row*HD + col] = f2b(acc[i][j][r] + bb);
            }
        }
    }
}

// ------- scores[m] = r[b] . item_bf[m] + s0[b], one wave per row -------
__global__ __launch_bounds__(256) void gp_scores(
    const float* __restrict__ rbuf, const float* __restrict__ s0buf,
    const unsigned short* __restrict__ item_bf, float* __restrict__ scores)
{
    const int m = blockIdx.x * 4 + (threadIdx.x >> 6);
    const int lane = threadIdx.x & 63;
    const int b = m >> 10;
    const unsigned short* ir = &item_bf[(size_t)m*HD + lane*8];
    const uint4 iv = *(const uint4*)ir;
    const float* rr = &rbuf[b*HD + lane*8];
    const float4 r0 = *(const float4*)rr;
    const float4 r1 = *(const float4*)(rr + 4);
    float acc = r0.x*b2f_lo(iv.x) + r0.y*b2f_hi(iv.x)
              + r0.z*b2f_lo(iv.y) + r0.w*b2f_hi(iv.y)
              + r1.x*b2f_lo(iv.z) + r1.y*b2f_hi(iv.z)
              + r1.z*b2f_lo(iv.w) + r1.w*b2f_hi(iv.w);
    #pragma unroll
    for (int off = 32; off; off >>= 1) acc += __shfl_down(acc, off);
    if (lane == 0) scores[m] = acc + s0buf[b];
}

// ----- gather + softmax + weighted sum of v: one wave per row -----
__global__ __launch_bounds__(256) void gp_attn(
    const float* __restrict__ scores, const int* __restrict__ index,
    const float* __restrict__ mask, const unsigned short* __restrict__ v,
    unsigned short* __restrict__ attn)
{
    const int bid = blockIdx.x;
    const int m = ((bid & 7) << 11) | ((bid >> 3) << 2) | (int)(threadIdx.x >> 6);
    const int lane = threadIdx.x & 63;
    const int b = m >> 10, l = m & 1023;

    const int t = lane & 31;
    const int idx = index[l*KNBR + t];
    const float s = scores[b*LL + idx] + mask[(size_t)m*KNBR + t];

    float mx = s;
    #pragma unroll
    for (int off = 16; off; off >>= 1) mx = fmaxf(mx, __shfl_xor(mx, off));
    const float e = __expf(s - mx);
    float sum = e;
    #pragma unroll
    for (int off = 16; off; off >>= 1) sum += __shfl_xor(sum, off);
    const float w = e / sum;

    const unsigned short* vb = v + (size_t)(b << 10) * HD;
    const int loff = lane * 8;
    float a[8] = {};
    #pragma unroll 8
    for (int t2 = 0; t2 < KNBR; t2++) {
        const int   it = __builtin_amdgcn_readlane(idx, t2);              // SGPR
        const float wt = __int_as_float(
            __builtin_amdgcn_readlane(__float_as_int(w), t2));            // SGPR
        const uint4 pv = *(const uint4*)(vb + (size_t)it*HD + loff);
        a[0] += wt * b2f_lo(pv.x); a[1] += wt * b2f_hi(pv.x);
        a[2] += wt * b2f_lo(pv.y); a[3] += wt * b2f_hi(pv.y);
        a[4] += wt * b2f_lo(pv.z); a[5] += wt * b2f_hi(pv.z);
        a[6] += wt * b2f_lo(pv.w); a[7] += wt * b2f_hi(pv.w);
    }
    uint4 o;
    o.x = (unsigned int)f2b(a[0]) | ((unsigned int)f2b(a[1]) << 16);
    o.y = (unsigned int)f2b(a[2]) | ((unsigned int)f2b(a[3]) << 16);
    o.z = (unsigned int)f2b(a[4]) | ((unsigned int)f2b(a[5]) << 16);
    o.w = (unsigned int)f2b(a[6]) | ((unsigned int)f2b(a[7]) << 16);
    *(uint4*)&attn[(size_t)m*HD + lane*8] = o;
}

// ------- dense GEMM + residual + LayerNorm fused -------
// 32 rows x 512 cols, 256 threads, 512 blocks = 2/CU. W from K-tiled Wd
// (contiguous staging). Residual staged via LDS (coalesced uint4), stride
// 528 ushorts -> conflict-free ds_read_u16.
__global__ __launch_bounds__(256) void dense_ln(
    const unsigned short* __restrict__ A,    // attn_bf, MT x 512 (row-major)
    const unsigned short* __restrict__ Wt,   // Wd K-tiled, 16 x [512][32]
    const float* __restrict__ bd, const unsigned short* __restrict__ res,
    const float* __restrict__ ln_g, const float* __restrict__ ln_b,
    float* __restrict__ out)
{
    __shared__ unsigned short As[2][32 * 32];    // 4 KB
    __shared__ unsigned short Bs[2][512 * 32];   // 64 KB (reused for res tile)
    __shared__ float rsum[4][32], rsq[4][32];    // 1 KB

    const int tid  = threadIdx.x;
    const int wave = tid >> 6, lane = tid & 63;
    const int row0 = blockIdx.x * 32;

    const int lrr = lane >> 2;
    const int cc  = lane & 3;
    const int fr   = lane & 15;
    const int quad = lane >> 4;

    f32x4 acc[2][8];
    #pragma unroll
    for (int i = 0; i < 2; i++)
        #pragma unroll
        for (int j = 0; j < 8; j++)
            acc[i][j] = (f32x4){0.f, 0.f, 0.f, 0.f};

    int a_off[2], b_off[8];
    #pragma unroll
    for (int i = 0; i < 2; i++) {
        const int m = i*16 + fr;
        a_off[i] = m*32 + ((quad ^ ((m >> 1) & 3)) << 3);
    }
    #pragma unroll
    for (int j = 0; j < 8; j++) {
        const int n = wave*128 + j*16 + fr;
        b_off[j] = n*32 + ((quad ^ ((n >> 1) & 3)) << 3);
    }

    // waves 0,1: 9 loads/tile (8 W + 1 A); waves 2,3: 8
    auto stage = [&](int bf, int kt) {
        #pragma unroll
        for (int t = 0; t < 8; t++) {
            const int n   = wave*128 + t*16 + lrr;
            const int gch = cc ^ ((n >> 1) & 3);
            const unsigned short* gw = &Wt[((size_t)kt*512 + n)*32 + gch*8];
            __builtin_amdgcn_global_load_lds(
                (const __attribute__((address_space(1))) void*)gw,
                (__attribute__((address_space(3))) void*)&Bs[bf][(wave*128 + t*16)*32],
                16, 0, 0);
        }
        if (wave < 2) {
            const int mm  = wave*16 + lrr;
            const int gch = cc ^ ((mm >> 1) & 3);
            const unsigned short* ga = &A[(size_t)(row0 + mm)*HD + kt*32 + gch*8];
            __builtin_amdgcn_global_load_lds(
                (const __attribute__((address_space(1))) void*)ga,
                (__attribute__((address_space(3))) void*)&As[bf][(wave*16)*32],
                16, 0, 0);
        }
    };

    stage(0, 0);     // tile 0
    stage(1, 1);     // tile 1 (in flight across the first barrier)

    for (int s = 0; s < 15; ++s) {
        if (wave < 2) asm volatile("s_waitcnt vmcnt(9)" ::: "memory");
        else          asm volatile("s_waitcnt vmcnt(8)" ::: "memory");
        __builtin_amdgcn_s_barrier();
        asm volatile("" ::: "memory");

        const int cur = s & 1;
        bf16x8 af[2], bfr[8];
        #pragma unroll
        for (int i = 0; i < 2; i++) af[i] = *(const bf16x8*)&As[cur][a_off[i]];
        #pragma unroll
        for (int j = 0; j < 8; j++) bfr[j] = *(const bf16x8*)&Bs[cur][b_off[j]];
        asm volatile("s_waitcnt lgkmcnt(0)" ::: "memory");
        __builtin_amdgcn_sched_barrier(0);     // rule #18
        __builtin_amdgcn_s_barrier();

        if (s + 2 < 16) stage(cur, s + 2);

        __builtin_amdgcn_s_setprio(1);
        #pragma unroll
        for (int i = 0; i < 2; i++)
            #pragma unroll
            for (int j = 0; j < 8; j++)
                acc[i][j] = __builtin_amdgcn_mfma_f32_16x16x32_bf16(
                    af[i], bfr[j], acc[i][j], 0, 0, 0);
        __builtin_amdgcn_s_setprio(0);
    }
    {   // final K-step (s=15): full drain
        asm volatile("s_waitcnt vmcnt(0)" ::: "memory");
        __builtin_amdgcn_s_barrier();
        asm volatile("" ::: "memory");
        bf16x8 af[2], bfr[8];
        #pragma unroll
        for (int i = 0; i < 2; i++) af[i] = *(const bf16x8*)&As[1][a_off[i]];
        #pragma unroll
        for (int j = 0; j < 8; j++) bfr[j] = *(const bf16x8*)&Bs[1][b_off[j]];
        asm volatile("s_waitcnt lgkmcnt(0)" ::: "memory");
        __builtin_amdgcn_sched_barrier(0);
        #pragma unroll
        for (int i = 0; i < 2; i++)
            #pragma unroll
            for (int j = 0; j < 8; j++)
                acc[i][j] = __builtin_amdgcn_mfma_f32_16x16x32_bf16(
                    af[i], bfr[j], acc[i][j], 0, 0, 0);
    }
    __syncthreads();   // all waves done with Bs -> safe to reuse for res

    // stage residual tile (32 x 512) into LDS, stride 528 (bank-clean)
    unsigned short* rs = (unsigned short*)Bs;   // 32*528*2 = 33.8 KB < 64 KB
    #pragma unroll
    for (int u = 0; u < 8; u++) {
        const int id = tid*8 + u;          // 0..2047
        const int rr = id >> 6, c8 = id & 63;
        *(uint4*)&rs[rr*528 + c8*8] =
            *(const uint4*)&res[(size_t)(row0 + rr)*HD + c8*8];
    }
    __syncthreads();

    float bdv[8], gv[8], lbv[8];
    #pragma unroll
    for (int j = 0; j < 8; j++) {
        const int col = wave*128 + j*16 + fr;
        bdv[j] = bd[col]; gv[j] = ln_g[col]; lbv[j] = ln_b[col];
    }

    #pragma unroll
    for (int i = 0; i < 2; i++) {
        #pragma unroll
        for (int r = 0; r < 4; r++) {
            const int lrow = i*16 + quad*4 + r;
            float a1 = 0.f, a2 = 0.f;
            #pragma unroll
            for (int j = 0; j < 8; j++) {
                const int col = wave*128 + j*16 + fr;
                float val = acc[i][j][r] + bdv[j] + b2f(rs[lrow*528 + col]);
                acc[i][j][r] = val;
                a1 += val; a2 += val*val;
            }
            #pragma unroll
            for (int off = 1; off < 16; off <<= 1) {
                a1 += __shfl_xor(a1, off);
                a2 += __shfl_xor(a2, off);
            }
            if (fr == 0) { rsum[wave][lrow] = a1; rsq[wave][lrow] = a2; }
        }
    }
    __syncthreads();

    #pragma unroll
    for (int i = 0; i < 2; i++) {
        #pragma unroll
        for (int r = 0; r < 4; r++) {
            const int lrow = i*16 + quad*4 + r;
            const float tot  = rsum[0][lrow] + rsum[1][lrow] + rsum[2][lrow] + rsum[3][lrow];
            const float tot2 = rsq[0][lrow]  + rsq[1][lrow]  + rsq[2][lrow]  + rsq[3][lrow];
            const float mu  = tot * (1.f/HD);
            const float var = tot2 * (1.f/HD) - mu*mu;
            const float inv = rsqrtf(var + 1e-12f);
            const size_t gr = (size_t)(row0 + lrow) * HD;
            #pragma unroll
            for (int j = 0; j < 8; j++) {
                const int col = wave*128 + j*16 + fr;
                out[gr + col] = (acc[i][j][r] - mu)*inv*gv[j] + lbv[j];
            }
        }
    }
}

extern "C" void kernel_launch(void* const* d_in, const int* in_sizes, int n_in,
                              void* d_out, int out_size, void* d_ws, size_t ws_size,
                              hipStream_t stream) {
    const float* user_emb = (const float*)d_in[0];
    const float* item_emb = (const float*)d_in[1];
    const float* mask     = (const float*)d_in[2];
    const int*   index    = (const int*)  d_in[3];
    const float* Wq = (const float*)d_in[4];  const float* bq = (const float*)d_in[5];
    const float* Wk = (const float*)d_in[6];  const float* bk = (const float*)d_in[7];
    const float* Wv = (const float*)d_in[8];  const float* bv = (const float*)d_in[9];
    const float* Wd = (const float*)d_in[10]; const float* bd = (const float*)d_in[11];
    const float* ln_g = (const float*)d_in[12];
    const float* ln_b = (const float*)d_in[13];

    float* out = (float*)d_out;

    char* p = (char*)d_ws;
    unsigned short* item_bf = (unsigned short*)p; p += (size_t)MT*HD*2;     // 16.8 MB
    unsigned short* item_kt = (unsigned short*)p; p += (size_t)MT*HD*2;     // 16.8 MB
    unsigned short* v_bf    = (unsigned short*)p; p += (size_t)MT*HD*2;     // 16.8 MB
    unsigned short* attn_bf = (unsigned short*)p; p += (size_t)MT*HD*2;     // 16.8 MB
    unsigned short* Wv_bf   = (unsigned short*)p; p += (size_t)HD*HD*2;     // 0.5 MB
    unsigned short* Wd_bf   = (unsigned short*)p; p += (size_t)HD*HD*2;     // 0.5 MB
    float* q      = (float*)p; p += 16*HD*4;
    float* rbuf   = (float*)p; p += 16*HD*4;
    float* s0buf  = (float*)p; p += 16*4;
    float* scores = (float*)p; p += MT*4;

    // L1: convs + q projection (K-tiled weight/item emission)
    prep<<<PB_CONV_I + PB_CONV_W + PB_Q, 256, 0, stream>>>(
        item_emb, Wv, Wd, user_emb, Wq, bq,
        item_bf, item_kt, Wv_bf, Wd_bf, q);

    // L2: V GEMM + r matvec + s0 (contiguous K-tile staging)
    gemm_v_r<<<656, 256, 0, stream>>>(item_kt, Wv_bf, bv, Wk, bk, q,
                                      v_bf, rbuf, s0buf);

    // L3: scores[m] = r[b].item_bf[m] + s0[b]
    gp_scores<<<MT/4, 256, 0, stream>>>(rbuf, s0buf, item_bf, scores);

    // L4: gather + softmax + PV -> attn_bf
    gp_attn<<<MT/4, 256, 0, stream>>>(scores, index, mask, v_bf, attn_bf);

    // L5: dense + residual + LN -> fp32 out (K-tiled Wd, LDS residual)
    dense_ln<<<MT/32, 256, 0, stream>>>(attn_bf, Wd_bf, bd, item_bf,
                                        ln_g, ln_b, out);
}